// Round 10
// baseline (211.268 us; speedup 1.0000x reference)
//
#include <hip/hip_runtime.h>

#define NHEADS 16
#define HDIM   64
#define HID    1024
#define BATCH  8
#define LW     512
#define LE     64
#define SEQ    576            // LW + LE
#define MTOT   (BATCH * SEQ)  // 4608

typedef unsigned short u16;
typedef __bf16 bf16x8 __attribute__((ext_vector_type(8)));
typedef float  f32x4  __attribute__((ext_vector_type(4)));

__device__ __forceinline__ u16 f2bf(float f) {
  union { float f; unsigned int i; } x;
  x.f = f;
  unsigned int u = x.i;
  unsigned int r = (u + 0x7FFFu + ((u >> 16) & 1u)) >> 16;
  return (u16)r;
}
__device__ __forceinline__ unsigned int pk2(float a, float b) {
  return (unsigned int)f2bf(a) | ((unsigned int)f2bf(b) << 16);
}

// async global->LDS, 16B/lane. Per-lane LDS ptr must equal wave base + lane*16.
__device__ __forceinline__ void gload16(const u16* g, u16* l) {
  __builtin_amdgcn_global_load_lds(
      (const __attribute__((address_space(1))) void*)g,
      (__attribute__((address_space(3))) void*)l, 16, 0, 0);
}

// ---------------------------------------------------------------------------
// Kernel 0: prep = weight transpose+cvt (blocks 0..4095) | x gather+cvt (rest)
// ---------------------------------------------------------------------------
__global__ __launch_bounds__(256) void prep_k(
    const float* __restrict__ w0, const float* __restrict__ w1,
    const float* __restrict__ w2, const float* __restrict__ w3,
    u16* __restrict__ wt,
    const float* __restrict__ word, const float* __restrict__ ent,
    u16* __restrict__ xb)
{
  const int bid = blockIdx.x, tid = threadIdx.x;
  if (bid < 4096) {
    __shared__ u16 tile[32][33];
    const int z = bid >> 10, rem = bid & 1023;
    const int bx = rem & 31, by = rem >> 5;
    const float* src = (z == 0) ? w0 : (z == 1) ? w1 : (z == 2) ? w2 : w3;
    u16* dst = wt + (size_t)z * HID * HID;
    const int tx = tid & 31, ty = tid >> 5;
    const int nx = bx * 32, ky = by * 32;
#pragma unroll
    for (int j = 0; j < 4; ++j)
      tile[ty * 4 + j][tx] = f2bf(src[(size_t)(ky + ty * 4 + j) * HID + nx + tx]);
    __syncthreads();
#pragma unroll
    for (int j = 0; j < 4; ++j)
      dst[(size_t)(nx + ty * 4 + j) * HID + ky + tx] = tile[tx][ty * 4 + j];
  } else {
    const int row = bid - 4096;
    const int bb = row / SEQ, ss = row - bb * SEQ;
    const float* src = (ss < LW) ? word + (size_t)(bb * LW + ss) * HID
                                 : ent  + (size_t)(bb * LE + (ss - LW)) * HID;
    float4 v = *(const float4*)(src + tid * 4);
    ushort4 o;
    o.x = f2bf(v.x); o.y = f2bf(v.y); o.z = f2bf(v.z); o.w = f2bf(v.w);
    *(ushort4*)(xb + (size_t)row * HID + tid * 4) = o;
  }
}

// ---------------------------------------------------------------------------
// Kernel 1: fused QKV GEMM. 64x128 tile (grid 1728 -> ~6 blocks/CU), BK=64
// single-buffer staging, swizzled. Wave wv owns 64 tokens x 32 cols.
// z: 0->Q, 1->K (swapped MFMA operands, b64-packed epilogue), 2->V (sigma-
// permuted keys for attn's register-direct PV).
// ---------------------------------------------------------------------------
__global__ __launch_bounds__(256) void qkv_gemm_k(
    const u16* __restrict__ xb, const u16* __restrict__ wt,
    const float* __restrict__ bq, const float* __restrict__ bk, const float* __restrict__ bv,
    u16* __restrict__ q_ws, u16* __restrict__ k_ws, u16* __restrict__ v_ws)
{
  __shared__ u16 sh[12288];            // 24576 B: As 64x64 | Bs 128x64; tb aliases
  u16* As = sh;                        // 4096 u16
  u16* Bs = sh + 4096;                 // 8192 u16
  const int which = blockIdx.z;
  const u16* W = wt + (size_t)which * HID * HID;
  const float* bias = (which == 0) ? bq : (which == 1) ? bk : bv;
  const int m0 = blockIdx.x * 64, n0 = blockIdx.y * 128;
  const int tid = threadIdx.x, lane = tid & 63, wv = tid >> 6;
  const int lr = lane & 15, quad = lane >> 4;
  const int wn = wv * 32;                       // wave's col offset in tile

  const int subrow = lane >> 3;
  const int gsw = ((lane & 7) ^ subrow) * 8;    // staged-granule k-offset
  const int fsw = lr & 7;                       // fragment-read XOR key

  const f32x4 fz = {0.f, 0.f, 0.f, 0.f};
  f32x4 acc[8];
#pragma unroll
  for (int i = 0; i < 8; ++i) acc[i] = fz;

  for (int ki = 0; ki < 16; ++ki) {
    const int k0 = ki * 64;
    // A: 64 rows (2 slots/wave), B: 128 rows (4 slots/wave)
#pragma unroll
    for (int j = 0; j < 2; ++j) {
      int row = (wv * 2 + j) * 8 + subrow;
      gload16(xb + (size_t)(m0 + row) * HID + k0 + gsw,
              As + ((wv * 2 + j) * 64 + lane) * 8);
    }
#pragma unroll
    for (int j = 0; j < 4; ++j) {
      int row = (wv * 4 + j) * 8 + subrow;
      gload16(W + (size_t)(n0 + row) * HID + k0 + gsw,
              Bs + ((wv * 4 + j) * 64 + lane) * 8);
    }
    __syncthreads();                           // staging visible
#pragma unroll
    for (int ks = 0; ks < 2; ++ks) {
      const int kc = (((ks * 4 + quad) ^ fsw) * 8);
      bf16x8 af[4], bfr[2];
#pragma unroll
      for (int i = 0; i < 4; ++i)
        af[i] = *(const bf16x8*)(&As[(i * 16 + lr) * 64 + kc]);
#pragma unroll
      for (int i = 0; i < 2; ++i)
        bfr[i] = *(const bf16x8*)(&Bs[(wn + i * 16 + lr) * 64 + kc]);
      if (which < 2) {
#pragma unroll
        for (int a = 0; a < 2; ++a)            // a: col tile (W rows as M)
#pragma unroll
          for (int b = 0; b < 4; ++b)          // b: token tile (as N)
            acc[a * 4 + b] = __builtin_amdgcn_mfma_f32_16x16x32_bf16(bfr[a], af[b], acc[a * 4 + b], 0, 0, 0);
      } else {
#pragma unroll
        for (int mi = 0; mi < 4; ++mi)
#pragma unroll
          for (int ni = 0; ni < 2; ++ni)
            acc[mi * 2 + ni] = __builtin_amdgcn_mfma_f32_16x16x32_bf16(af[mi], bfr[ni], acc[mi * 2 + ni], 0, 0, 0);
      }
    }
    __syncthreads();                           // reads done before next staging
  }

  // epilogue: 2 per-head transpose buffers 64x68; waves (0,1)->head0, (2,3)->head1
  const int hl = wn >> 6;                      // head_local
  const int wnh = wn & 63;                     // 0 or 32 within head
  u16* tg = sh + hl * (64 * 68);
  const int bb = m0 / SEQ, ssb = m0 - bb * SEQ;   // m0 64-aligned, no batch cross
  const int headg = (n0 >> 6) + hl;
  const int sub = wv & 1;

  if (which < 2) {
    // swapped acc[a*4+b]: d = wnh + a*16 + quad*4 + r, token = b*16 + lr
    float4 bias4[2];
#pragma unroll
    for (int a = 0; a < 2; ++a)
      bias4[a] = *(const float4*)(bias + n0 + wn + a * 16 + quad * 4);
#pragma unroll
    for (int b = 0; b < 4; ++b)
#pragma unroll
      for (int a = 0; a < 2; ++a) {
        uint2 w2v;
        w2v.x = pk2(acc[a * 4 + b][0] + bias4[a].x, acc[a * 4 + b][1] + bias4[a].y);
        w2v.y = pk2(acc[a * 4 + b][2] + bias4[a].z, acc[a * 4 + b][3] + bias4[a].w);
        *(uint2*)(&tg[(b * 16 + lr) * 68 + wnh + a * 16 + quad * 4]) = w2v;
      }
    __syncthreads();
    u16* drow = (which == 0 ? q_ws : k_ws)
              + ((size_t)(bb * NHEADS + headg) * SEQ + ssb) * HDIM;
#pragma unroll
    for (int i = 0; i < 4; ++i) {
      int rrow = sub * 32 + i * 8 + (lane >> 3);
      int seg = lane & 7;
      bf16x8 v8 = *(const bf16x8*)(&tg[rrow * 68 + seg * 8]);
      *(bf16x8*)(drow + (size_t)rrow * HDIM + seg * 8) = v8;
    }
  } else {
    // normal acc[mi*2+ni]: d = wnh + ni*16 + lr, sigma(token) r-consecutive
    float bcol[2];
#pragma unroll
    for (int ni = 0; ni < 2; ++ni) bcol[ni] = bias[n0 + wn + ni * 16 + lr];
#pragma unroll
    for (int mi = 0; mi < 4; ++mi)
#pragma unroll
      for (int ni = 0; ni < 2; ++ni) {
        uint2 w2v;
        w2v.x = pk2(acc[mi * 2 + ni][0] + bcol[ni], acc[mi * 2 + ni][1] + bcol[ni]);
        w2v.y = pk2(acc[mi * 2 + ni][2] + bcol[ni], acc[mi * 2 + ni][3] + bcol[ni]);
        *(uint2*)(&tg[(wnh + ni * 16 + lr) * 68 + (mi >> 1) * 32 + quad * 8 + (mi & 1) * 4]) = w2v;
      }
    __syncthreads();
    u16* dcol = v_ws + ((size_t)(bb * NHEADS + headg) * HDIM) * SEQ + ssb;
#pragma unroll
    for (int i = 0; i < 4; ++i) {
      int d = sub * 32 + i * 8 + (lane >> 3);
      int seg = lane & 7;
      bf16x8 v8 = *(const bf16x8*)(&tg[d * 68 + seg * 8]);
      *(bf16x8*)(dcol + (size_t)d * SEQ + seg * 8) = v8;
    }
  }
}

// ---------------------------------------------------------------------------
// Kernel 2: flash attention, no-max softmax, register-direct PV. SINGLE-BUFFER
// K/V staging (18.7 KB LDS -> grid-limited ~4.5 blocks/CU resident).
// ---------------------------------------------------------------------------
__global__ __launch_bounds__(256) void attn_k(
    const u16* __restrict__ q_ws, const u16* __restrict__ k_ws,
    const u16* __restrict__ v_ws, const float* __restrict__ mask,
    u16* __restrict__ ctxh)
{
  __shared__ u16 Ks[4096];
  __shared__ u16 Vs[4096];
  __shared__ float ms[576];
  const int bhx = blockIdx.x, qt = blockIdx.y;
  const int b = bhx >> 4, h = bhx & 15;
  const int tid = threadIdx.x, lane = tid & 63, wv = tid >> 6;
  const int lr = lane & 15, quad = lane >> 4;
  const int q0 = qt * 64 + wv * 16;
  const u16* kbh = k_ws + (size_t)bhx * SEQ * HDIM;
  const u16* vbh = v_ws + (size_t)bhx * HDIM * SEQ;
  const u16* qp  = q_ws + ((size_t)bhx * SEQ + q0) * HDIM;
  const float* mrow = mask + b * SEQ;

  if (tid < 144) *(float4*)(&ms[tid * 4]) = *(const float4*)(mrow + tid * 4);

  const int subrow = lane >> 3;
  const int gsw = (lane & 7) ^ subrow;

  bf16x8 qf[2];
  qf[0] = *(const bf16x8*)(qp + lr * HDIM + quad * 8);
  qf[1] = *(const bf16x8*)(qp + lr * HDIM + 32 + quad * 8);

  const f32x4 fz = {0.f, 0.f, 0.f, 0.f};
  f32x4 oa[4] = {fz, fz, fz, fz};
  f32x4 rsv = fz;
  const int fA = lr & 7;

  for (int ci = 0; ci < 9; ++ci) {
    const int c = ci * 64;
#pragma unroll
    for (int j = 0; j < 2; ++j) {
      int row = (wv * 2 + j) * 8 + subrow;
      gload16(kbh + ((size_t)(c + row)) * HDIM + gsw * 8,
              &Ks[((wv * 2 + j) * 64 + lane) * 8]);
      gload16(vbh + (size_t)row * SEQ + c + gsw * 8,
              &Vs[((wv * 2 + j) * 64 + lane) * 8]);
    }
    __syncthreads();                       // staging visible (+ ms on ci=0)
    f32x4 s[4] = {fz, fz, fz, fz};
#pragma unroll
    for (int ks = 0; ks < 2; ++ks)
#pragma unroll
      for (int t = 0; t < 4; ++t) {
        bf16x8 kf = *(const bf16x8*)(&Ks[(t * 16 + lr) * 64 + (((ks * 4 + quad) ^ fA) * 8)]);
        s[t] = __builtin_amdgcn_mfma_f32_16x16x32_bf16(kf, qf[ks], s[t], 0, 0, 0);
      }
    unsigned int pk0[4], pk1[4];
#pragma unroll
    for (int t = 0; t < 4; ++t) {
      float4 mv = *(const float4*)(&ms[c + t * 16 + quad * 4]);
      s[t][0] = __expf(s[t][0] * 0.125f + mv.x);
      s[t][1] = __expf(s[t][1] * 0.125f + mv.y);
      s[t][2] = __expf(s[t][2] * 0.125f + mv.z);
      s[t][3] = __expf(s[t][3] * 0.125f + mv.w);
      rsv += s[t];
      pk0[t] = pk2(s[t][0], s[t][1]);
      pk1[t] = pk2(s[t][2], s[t][3]);
    }
#pragma unroll
    for (int ks = 0; ks < 2; ++ks) {
      union { unsigned int u[4]; bf16x8 v; } ap;
      ap.u[0] = pk0[ks * 2];     ap.u[1] = pk1[ks * 2];
      ap.u[2] = pk0[ks * 2 + 1]; ap.u[3] = pk1[ks * 2 + 1];
#pragma unroll
      for (int n = 0; n < 4; ++n) {
        bf16x8 vf = *(const bf16x8*)(&Vs[(n * 16 + lr) * 64 + (((ks * 4 + quad) ^ fA) * 8)]);
        oa[n] = __builtin_amdgcn_mfma_f32_16x16x32_bf16(ap.v, vf, oa[n], 0, 0, 0);
      }
    }
    __syncthreads();                       // reads done before next staging
  }

  float rl = rsv[0] + rsv[1] + rsv[2] + rsv[3];
  rl += __shfl_xor(rl, 16);
  rl += __shfl_xor(rl, 32);
  float inv = 1.0f / rl;
  float invr[4];
#pragma unroll
  for (int r = 0; r < 4; ++r) invr[r] = __shfl(inv, quad * 4 + r);

  // epilogue scratch aliases Ks/Vs (all reads drained at final barrier)
  u16* pw = (wv < 2) ? &Ks[wv * 2048] : &Vs[(wv - 2) * 2048];
#pragma unroll
  for (int n = 0; n < 4; ++n)
#pragma unroll
    for (int r = 0; r < 4; ++r)
      pw[(quad * 4 + r) * 68 + n * 16 + lr] = f2bf(oa[n][r] * invr[r]);
  const int token0 = b * SEQ + q0;
  u16* cb = ctxh + ((size_t)h * MTOT + token0) * HDIM;
#pragma unroll
  for (int i = 0; i < 2; ++i) {
    int row = lane & 15;
    int seg = (lane >> 4) + i * 4;
    bf16x8 v8 = *(const bf16x8*)(&pw[row * 68 + seg * 8]);
    *(bf16x8*)(cb + (size_t)row * HDIM + seg * 8) = v8;
  }
}

// ---------------------------------------------------------------------------
// Kernel 3: output projection + bias + residual. 32x128 tile (grid 1152 ->
// ~4.5 blocks/CU), BK=64 single-buffer staging. f32 y, direct stores.
// ---------------------------------------------------------------------------
__global__ __launch_bounds__(256) void out_gemm_k(
    const u16* __restrict__ ctxh, const u16* __restrict__ wto,
    const float* __restrict__ bo,
    const float* __restrict__ word, const float* __restrict__ ent,
    float* __restrict__ y)
{
  __shared__ u16 sh[10240];            // 20480 B: As 32x64 | Bs 128x64
  u16* As = sh;                        // 2048 u16
  u16* Bs = sh + 2048;                 // 8192 u16
  const int m0 = blockIdx.x * 32, n0 = blockIdx.y * 128;
  const int tid = threadIdx.x, lane = tid & 63, wv = tid >> 6;
  const int lr = lane & 15, quad = lane >> 4;
  const int wn = wv * 32;
  const int subrow = lane >> 3;
  const int gsw = ((lane & 7) ^ subrow) * 8;
  const int fsw = lr & 7;

  const f32x4 fz = {0.f, 0.f, 0.f, 0.f};
  f32x4 acc[2][2];
#pragma unroll
  for (int mi = 0; mi < 2; ++mi)
#pragma unroll
    for (int ni = 0; ni < 2; ++ni) acc[mi][ni] = fz;

  for (int hb = 0; hb < 16; ++hb) {            // k0 = hb*64
    {
      int row = wv * 8 + subrow;               // A: 32 rows, 1 slot/wave
      gload16(ctxh + ((size_t)hb * MTOT + (m0 + row)) * HDIM + gsw,
              As + (wv * 64 + lane) * 8);
    }
#pragma unroll
    for (int j = 0; j < 4; ++j) {              // B: 128 rows, 4 slots/wave
      int row = (wv * 4 + j) * 8 + subrow;
      gload16(wto + (size_t)(n0 + row) * HID + hb * 64 + gsw,
              Bs + ((wv * 4 + j) * 64 + lane) * 8);
    }
    __syncthreads();
#pragma unroll
    for (int ks = 0; ks < 2; ++ks) {
      const int kc = (((ks * 4 + quad) ^ fsw) * 8);
      bf16x8 af[2], bfr[2];
#pragma unroll
      for (int i = 0; i < 2; ++i) {
        af[i]  = *(const bf16x8*)(&As[(i * 16 + lr) * 64 + kc]);
        bfr[i] = *(const bf16x8*)(&Bs[(wn + i * 16 + lr) * 64 + kc]);
      }
#pragma unroll
      for (int mi = 0; mi < 2; ++mi)
#pragma unroll
        for (int ni = 0; ni < 2; ++ni)
          acc[mi][ni] = __builtin_amdgcn_mfma_f32_16x16x32_bf16(af[mi], bfr[ni], acc[mi][ni], 0, 0, 0);
    }
    __syncthreads();
  }

#pragma unroll
  for (int mi = 0; mi < 2; ++mi) {
    int rowb = m0 + mi * 16 + quad * 4;
#pragma unroll
    for (int r = 0; r < 4; ++r) {
      int row = rowb + r;
      int bb = row / SEQ, ss = row - bb * SEQ;
      const float* res = (ss < LW) ? (word + (size_t)(bb * LW + ss) * HID)
                                   : (ent  + (size_t)(bb * LE + (ss - LW)) * HID);
#pragma unroll
      for (int ni = 0; ni < 2; ++ni) {
        int col = n0 + wn + ni * 16 + lr;
        y[(size_t)row * HID + col] = acc[mi][ni][r] + bo[col] + res[col];
      }
    }
  }
}

// ---------------------------------------------------------------------------
// Kernel 4: LayerNorm per token + scatter into word|entity output split (f32)
// ---------------------------------------------------------------------------
__global__ __launch_bounds__(256) void ln_k(
    const float* __restrict__ y, const float* __restrict__ lnw,
    const float* __restrict__ lnb, float* __restrict__ out)
{
  const int row = blockIdx.x;
  const int tid = threadIdx.x;
  __shared__ float ssum[4], sqq[4];

  const float* yr = y + (size_t)row * HID;
  float4 v = *(const float4*)(yr + tid * 4);
  float s = v.x + v.y + v.z + v.w;
  float q = v.x * v.x + v.y * v.y + v.z * v.z + v.w * v.w;
#pragma unroll
  for (int o = 32; o > 0; o >>= 1) { s += __shfl_xor(s, o); q += __shfl_xor(q, o); }
  if ((tid & 63) == 0) { ssum[tid >> 6] = s; sqq[tid >> 6] = q; }
  __syncthreads();
  s = ssum[0] + ssum[1] + ssum[2] + ssum[3];
  q = sqq[0] + sqq[1] + sqq[2] + sqq[3];
  float mean = s * (1.0f / HID);
  float var  = q * (1.0f / HID) - mean * mean;
  float rstd = rsqrtf(var + 1e-12f);

  int bb = row / SEQ, ss2 = row - bb * SEQ;
  float* dst = (ss2 < LW)
             ? out + (size_t)(bb * LW + ss2) * HID
             : out + (size_t)BATCH * LW * HID + (size_t)(bb * LE + (ss2 - LW)) * HID;

  float4 w4 = *(const float4*)(lnw + tid * 4);
  float4 b4 = *(const float4*)(lnb + tid * 4);
  float4 o4;
  o4.x = w4.x * (v.x - mean) * rstd + b4.x;
  o4.y = w4.y * (v.y - mean) * rstd + b4.y;
  o4.z = w4.z * (v.z - mean) * rstd + b4.z;
  o4.w = w4.w * (v.w - mean) * rstd + b4.w;
  *(float4*)(dst + tid * 4) = o4;
}

// ---------------------------------------------------------------------------
extern "C" void kernel_launch(void* const* d_in, const int* in_sizes, int n_in,
                              void* d_out, int out_size, void* d_ws, size_t ws_size,
                              hipStream_t stream) {
  const float* word = (const float*)d_in[0];
  const float* ent  = (const float*)d_in[1];
  const float* mask = (const float*)d_in[2];
  const float* Wq   = (const float*)d_in[3];
  const float* bq   = (const float*)d_in[4];
  const float* Wk   = (const float*)d_in[5];
  const float* bk   = (const float*)d_in[6];
  const float* Wv   = (const float*)d_in[7];
  const float* bv   = (const float*)d_in[8];
  const float* Wo   = (const float*)d_in[9];
  const float* bo   = (const float*)d_in[10];
  const float* lnw  = (const float*)d_in[11];
  const float* lnb  = (const float*)d_in[12];

  char* base = (char*)d_ws;
  u16*   wt   = (u16*)base;                               // 8 MB
  u16*   q_ws = (u16*)(base + (size_t)8 * 1024 * 1024);   // 9.44 MB each
  u16*   k_ws = q_ws + (size_t)MTOT * HID;
  u16*   v_ws = k_ws + (size_t)MTOT * HID;
  u16*   ctxh = v_ws + (size_t)MTOT * HID;                // [h][M][64]
  char*  xy   = (char*)(ctxh + (size_t)MTOT * HID);
  u16*   xb   = (u16*)xy;                                 // aliases y (disjoint life)
  float* y    = (float*)xy;

  hipLaunchKernelGGL(prep_k, dim3(4096 + MTOT), dim3(256), 0, stream,
                     Wq, Wk, Wv, Wo, wt, word, ent, xb);
  hipLaunchKernelGGL(qkv_gemm_k, dim3(MTOT / 64, HID / 128, 3), dim3(256), 0, stream,
                     xb, wt, bq, bk, bv, q_ws, k_ws, v_ws);
  hipLaunchKernelGGL(attn_k, dim3(BATCH * NHEADS, SEQ / 64), dim3(256), 0, stream,
                     q_ws, k_ws, v_ws, mask, ctxh);
  hipLaunchKernelGGL(out_gemm_k, dim3(MTOT / 32, HID / 128), dim3(256), 0, stream,
                     ctxh, wt + (size_t)3 * HID * HID, bo, word, ent, y);
  hipLaunchKernelGGL(ln_k, dim3(MTOT), dim3(256), 0, stream,
                     y, lnw, lnb, (float*)d_out);
}

// Round 11
// 195.714 us; speedup vs baseline: 1.0795x; 1.0795x over previous
//
#include <hip/hip_runtime.h>

#define NHEADS 16
#define HDIM   64
#define HID    1024
#define BATCH  8
#define LW     512
#define LE     64
#define SEQ    576            // LW + LE
#define MTOT   (BATCH * SEQ)  // 4608

typedef unsigned short u16;
typedef __bf16 bf16x8 __attribute__((ext_vector_type(8)));
typedef float  f32x4  __attribute__((ext_vector_type(4)));

__device__ __forceinline__ u16 f2bf(float f) {
  union { float f; unsigned int i; } x;
  x.f = f;
  unsigned int u = x.i;
  unsigned int r = (u + 0x7FFFu + ((u >> 16) & 1u)) >> 16;
  return (u16)r;
}
__device__ __forceinline__ unsigned int pk2(float a, float b) {
  return (unsigned int)f2bf(a) | ((unsigned int)f2bf(b) << 16);
}

// async global->LDS, 16B/lane. Per-lane LDS ptr must equal wave base + lane*16.
__device__ __forceinline__ void gload16(const u16* g, u16* l) {
  __builtin_amdgcn_global_load_lds(
      (const __attribute__((address_space(1))) void*)g,
      (__attribute__((address_space(3))) void*)l, 16, 0, 0);
}

// ---------------------------------------------------------------------------
// Kernel 0: prep = weight transpose+cvt (blocks 0..4095) | x gather+cvt (rest)
// ---------------------------------------------------------------------------
__global__ __launch_bounds__(256) void prep_k(
    const float* __restrict__ w0, const float* __restrict__ w1,
    const float* __restrict__ w2, const float* __restrict__ w3,
    u16* __restrict__ wt,
    const float* __restrict__ word, const float* __restrict__ ent,
    u16* __restrict__ xb)
{
  const int bid = blockIdx.x, tid = threadIdx.x;
  if (bid < 4096) {
    __shared__ u16 tile[32][33];
    const int z = bid >> 10, rem = bid & 1023;
    const int bx = rem & 31, by = rem >> 5;
    const float* src = (z == 0) ? w0 : (z == 1) ? w1 : (z == 2) ? w2 : w3;
    u16* dst = wt + (size_t)z * HID * HID;
    const int tx = tid & 31, ty = tid >> 5;
    const int nx = bx * 32, ky = by * 32;
#pragma unroll
    for (int j = 0; j < 4; ++j)
      tile[ty * 4 + j][tx] = f2bf(src[(size_t)(ky + ty * 4 + j) * HID + nx + tx]);
    __syncthreads();
#pragma unroll
    for (int j = 0; j < 4; ++j)
      dst[(size_t)(nx + ty * 4 + j) * HID + ky + tx] = tile[tx][ty * 4 + j];
  } else {
    const int row = bid - 4096;
    const int bb = row / SEQ, ss = row - bb * SEQ;
    const float* src = (ss < LW) ? word + (size_t)(bb * LW + ss) * HID
                                 : ent  + (size_t)(bb * LE + (ss - LW)) * HID;
    float4 v = *(const float4*)(src + tid * 4);
    ushort4 o;
    o.x = f2bf(v.x); o.y = f2bf(v.y); o.z = f2bf(v.z); o.w = f2bf(v.w);
    *(ushort4*)(xb + (size_t)row * HID + tid * 4) = o;
  }
}

// ---------------------------------------------------------------------------
// Kernel 1: fused QKV GEMM (R9-measured best: 128x128 tile, BK=64, single-
// buffer swizzled staging). z: 0->Q, 1->K (swapped MFMA operands, b64-packed
// epilogue), 2->V (sigma-permuted keys for attn's register-direct PV).
// ---------------------------------------------------------------------------
__global__ __launch_bounds__(256) void qkv_gemm_k(
    const u16* __restrict__ xb, const u16* __restrict__ wt,
    const float* __restrict__ bq, const float* __restrict__ bk, const float* __restrict__ bv,
    u16* __restrict__ q_ws, u16* __restrict__ k_ws, u16* __restrict__ v_ws)
{
  __shared__ u16 sh[4 * 64 * 68];      // 34816 B; staging (2x8192 u16) + tb alias
  const int which = blockIdx.z;
  const u16* W = wt + (size_t)which * HID * HID;
  const float* bias = (which == 0) ? bq : (which == 1) ? bk : bv;
  const int m0 = blockIdx.x * 128, n0 = blockIdx.y * 128;
  const int tid = threadIdx.x, lane = tid & 63, wv = tid >> 6;
  const int lr = lane & 15, quad = lane >> 4;
  const int wm = (wv >> 1) * 64, wn = (wv & 1) * 64;

  const int subrow = lane >> 3;                 // row&7 within 8-row group
  const int gsw = ((lane & 7) ^ subrow) * 8;    // global k-offset (elems)
  const int fsw = lr & 7;                       // fragment-read XOR key

  u16* As = sh;                                 // 128 x 64
  u16* Bs = sh + 8192;

  const f32x4 fz = {0.f, 0.f, 0.f, 0.f};
  f32x4 acc[4][4];
#pragma unroll
  for (int a = 0; a < 4; ++a)
#pragma unroll
    for (int b = 0; b < 4; ++b) acc[a][b] = fz;

  for (int ki = 0; ki < 16; ++ki) {
    const int k0 = ki * 64;
#pragma unroll
    for (int j = 0; j < 4; ++j) {
      int row = (wv * 4 + j) * 8 + subrow;
      u16* ldst = sh + ((wv * 4 + j) * 64 + lane) * 8;   // As granule
      gload16(xb + (size_t)(m0 + row) * HID + k0 + gsw, ldst);
      gload16(W  + (size_t)(n0 + row) * HID + k0 + gsw, ldst + 8192);
    }
    __syncthreads();                           // staging visible
#pragma unroll
    for (int ks = 0; ks < 2; ++ks) {
      bf16x8 af[4], bfr[4];
#pragma unroll
      for (int i = 0; i < 4; ++i) {
        af[i]  = *(const bf16x8*)(&As[(wm + i * 16 + lr) * 64 + (((ks * 4 + quad) ^ fsw) * 8)]);
        bfr[i] = *(const bf16x8*)(&Bs[(wn + i * 16 + lr) * 64 + (((ks * 4 + quad) ^ fsw) * 8)]);
      }
      if (which < 2) {
#pragma unroll
        for (int a = 0; a < 4; ++a)            // a = ni (W rows as M)
#pragma unroll
          for (int b = 0; b < 4; ++b)          // b = mi (tokens as N)
            acc[a][b] = __builtin_amdgcn_mfma_f32_16x16x32_bf16(bfr[a], af[b], acc[a][b], 0, 0, 0);
      } else {
#pragma unroll
        for (int a = 0; a < 4; ++a)            // a = mi
#pragma unroll
          for (int b = 0; b < 4; ++b)          // b = ni
            acc[a][b] = __builtin_amdgcn_mfma_f32_16x16x32_bf16(af[a], bfr[b], acc[a][b], 0, 0, 0);
      }
    }
    __syncthreads();                           // reads done before next staging
  }

  // epilogue: per-wave 64x64 LDS transpose with packed b64 writes
  u16* tb = sh + wv * (64 * 68);
  const int head = (n0 + wn) >> 6;
  const int mbase = m0 + wm;                   // 64-aligned; never crosses batch
  const int bb = mbase / SEQ;
  const int ssb = mbase - bb * SEQ;

  if (which < 2) {
    // swapped acc: acc[ni][mi], element r: d = ni*16+quad*4+r, token = mi*16+lr
    float4 bias4[4];
#pragma unroll
    for (int ni = 0; ni < 4; ++ni)
      bias4[ni] = *(const float4*)(bias + n0 + wn + ni * 16 + quad * 4);
#pragma unroll
    for (int mi = 0; mi < 4; ++mi)
#pragma unroll
      for (int ni = 0; ni < 4; ++ni) {
        uint2 w2v;
        w2v.x = pk2(acc[ni][mi][0] + bias4[ni].x, acc[ni][mi][1] + bias4[ni].y);
        w2v.y = pk2(acc[ni][mi][2] + bias4[ni].z, acc[ni][mi][3] + bias4[ni].w);
        *(uint2*)(&tb[(mi * 16 + lr) * 68 + ni * 16 + quad * 4]) = w2v;
      }
    u16* drow = (which == 0 ? q_ws : k_ws)
              + ((size_t)(bb * NHEADS + head) * SEQ + ssb) * HDIM;
#pragma unroll
    for (int i = 0; i < 8; ++i) {
      int rrow = i * 8 + (lane >> 3);
      int seg = lane & 7;
      bf16x8 v8 = *(const bf16x8*)(&tb[rrow * 68 + seg * 8]);
      *(bf16x8*)(drow + (size_t)rrow * HDIM + seg * 8) = v8;
    }
  } else {
    // normal acc: acc[mi][ni], d = ni*16+lr, sigma(token) r-consecutive
    float bcol[4];
#pragma unroll
    for (int ni = 0; ni < 4; ++ni) bcol[ni] = bias[n0 + wn + ni * 16 + lr];
#pragma unroll
    for (int mi = 0; mi < 4; ++mi)
#pragma unroll
      for (int ni = 0; ni < 4; ++ni) {
        uint2 w2v;
        w2v.x = pk2(acc[mi][ni][0] + bcol[ni], acc[mi][ni][1] + bcol[ni]);
        w2v.y = pk2(acc[mi][ni][2] + bcol[ni], acc[mi][ni][3] + bcol[ni]);
        *(uint2*)(&tb[(ni * 16 + lr) * 68 + (mi >> 1) * 32 + quad * 8 + (mi & 1) * 4]) = w2v;
      }
    u16* dcol = v_ws + ((size_t)(bb * NHEADS + head) * HDIM) * SEQ + ssb;
#pragma unroll
    for (int i = 0; i < 8; ++i) {
      int d = i * 8 + (lane >> 3);
      int seg = lane & 7;
      bf16x8 v8 = *(const bf16x8*)(&tb[d * 68 + seg * 8]);
      *(bf16x8*)(dcol + (size_t)d * SEQ + seg * 8) = v8;
    }
  }
}

// ---------------------------------------------------------------------------
// Kernel 2: flash attention (R10-measured: single-buffer staging, 18.7 KB LDS)
// ---------------------------------------------------------------------------
__global__ __launch_bounds__(256) void attn_k(
    const u16* __restrict__ q_ws, const u16* __restrict__ k_ws,
    const u16* __restrict__ v_ws, const float* __restrict__ mask,
    u16* __restrict__ ctxh)
{
  __shared__ u16 Ks[4096];
  __shared__ u16 Vs[4096];
  __shared__ float ms[576];
  const int bhx = blockIdx.x, qt = blockIdx.y;
  const int b = bhx >> 4, h = bhx & 15;
  const int tid = threadIdx.x, lane = tid & 63, wv = tid >> 6;
  const int lr = lane & 15, quad = lane >> 4;
  const int q0 = qt * 64 + wv * 16;
  const u16* kbh = k_ws + (size_t)bhx * SEQ * HDIM;
  const u16* vbh = v_ws + (size_t)bhx * HDIM * SEQ;
  const u16* qp  = q_ws + ((size_t)bhx * SEQ + q0) * HDIM;
  const float* mrow = mask + b * SEQ;

  if (tid < 144) *(float4*)(&ms[tid * 4]) = *(const float4*)(mrow + tid * 4);

  const int subrow = lane >> 3;
  const int gsw = (lane & 7) ^ subrow;

  bf16x8 qf[2];
  qf[0] = *(const bf16x8*)(qp + lr * HDIM + quad * 8);
  qf[1] = *(const bf16x8*)(qp + lr * HDIM + 32 + quad * 8);

  const f32x4 fz = {0.f, 0.f, 0.f, 0.f};
  f32x4 oa[4] = {fz, fz, fz, fz};
  f32x4 rsv = fz;
  const int fA = lr & 7;

  for (int ci = 0; ci < 9; ++ci) {
    const int c = ci * 64;
#pragma unroll
    for (int j = 0; j < 2; ++j) {
      int row = (wv * 2 + j) * 8 + subrow;
      gload16(kbh + ((size_t)(c + row)) * HDIM + gsw * 8,
              &Ks[((wv * 2 + j) * 64 + lane) * 8]);
      gload16(vbh + (size_t)row * SEQ + c + gsw * 8,
              &Vs[((wv * 2 + j) * 64 + lane) * 8]);
    }
    __syncthreads();                       // staging visible (+ ms on ci=0)
    f32x4 s[4] = {fz, fz, fz, fz};
#pragma unroll
    for (int ks = 0; ks < 2; ++ks)
#pragma unroll
      for (int t = 0; t < 4; ++t) {
        bf16x8 kf = *(const bf16x8*)(&Ks[(t * 16 + lr) * 64 + (((ks * 4 + quad) ^ fA) * 8)]);
        s[t] = __builtin_amdgcn_mfma_f32_16x16x32_bf16(kf, qf[ks], s[t], 0, 0, 0);
      }
    unsigned int pk0[4], pk1[4];
#pragma unroll
    for (int t = 0; t < 4; ++t) {
      float4 mv = *(const float4*)(&ms[c + t * 16 + quad * 4]);
      s[t][0] = __expf(s[t][0] * 0.125f + mv.x);
      s[t][1] = __expf(s[t][1] * 0.125f + mv.y);
      s[t][2] = __expf(s[t][2] * 0.125f + mv.z);
      s[t][3] = __expf(s[t][3] * 0.125f + mv.w);
      rsv += s[t];
      pk0[t] = pk2(s[t][0], s[t][1]);
      pk1[t] = pk2(s[t][2], s[t][3]);
    }
#pragma unroll
    for (int ks = 0; ks < 2; ++ks) {
      union { unsigned int u[4]; bf16x8 v; } ap;
      ap.u[0] = pk0[ks * 2];     ap.u[1] = pk1[ks * 2];
      ap.u[2] = pk0[ks * 2 + 1]; ap.u[3] = pk1[ks * 2 + 1];
#pragma unroll
      for (int n = 0; n < 4; ++n) {
        bf16x8 vf = *(const bf16x8*)(&Vs[(n * 16 + lr) * 64 + (((ks * 4 + quad) ^ fA) * 8)]);
        oa[n] = __builtin_amdgcn_mfma_f32_16x16x32_bf16(ap.v, vf, oa[n], 0, 0, 0);
      }
    }
    __syncthreads();                       // reads done before next staging
  }

  float rl = rsv[0] + rsv[1] + rsv[2] + rsv[3];
  rl += __shfl_xor(rl, 16);
  rl += __shfl_xor(rl, 32);
  float inv = 1.0f / rl;
  float invr[4];
#pragma unroll
  for (int r = 0; r < 4; ++r) invr[r] = __shfl(inv, quad * 4 + r);

  // epilogue scratch aliases Ks/Vs (all reads drained at final barrier)
  u16* pw = (wv < 2) ? &Ks[wv * 2048] : &Vs[(wv - 2) * 2048];
#pragma unroll
  for (int n = 0; n < 4; ++n)
#pragma unroll
    for (int r = 0; r < 4; ++r)
      pw[(quad * 4 + r) * 68 + n * 16 + lr] = f2bf(oa[n][r] * invr[r]);
  const int token0 = b * SEQ + q0;
  u16* cb = ctxh + ((size_t)h * MTOT + token0) * HDIM;
#pragma unroll
  for (int i = 0; i < 2; ++i) {
    int row = lane & 15;
    int seg = (lane >> 4) + i * 4;
    bf16x8 v8 = *(const bf16x8*)(&pw[row * 68 + seg * 8]);
    *(bf16x8*)(cb + (size_t)row * HDIM + seg * 8) = v8;
  }
}

// ---------------------------------------------------------------------------
// Kernel 3: output projection + bias + residual (R10-measured: 32x128 tile,
// grid 1152, BK=64 single-buffer staging). f32 y, direct stores.
// ---------------------------------------------------------------------------
__global__ __launch_bounds__(256) void out_gemm_k(
    const u16* __restrict__ ctxh, const u16* __restrict__ wto,
    const float* __restrict__ bo,
    const float* __restrict__ word, const float* __restrict__ ent,
    float* __restrict__ y)
{
  __shared__ u16 sh[10240];            // 20480 B: As 32x64 | Bs 128x64
  u16* As = sh;                        // 2048 u16
  u16* Bs = sh + 2048;                 // 8192 u16
  const int m0 = blockIdx.x * 32, n0 = blockIdx.y * 128;
  const int tid = threadIdx.x, lane = tid & 63, wv = tid >> 6;
  const int lr = lane & 15, quad = lane >> 4;
  const int wn = wv * 32;
  const int subrow = lane >> 3;
  const int gsw = ((lane & 7) ^ subrow) * 8;
  const int fsw = lr & 7;

  const f32x4 fz = {0.f, 0.f, 0.f, 0.f};
  f32x4 acc[2][2];
#pragma unroll
  for (int mi = 0; mi < 2; ++mi)
#pragma unroll
    for (int ni = 0; ni < 2; ++ni) acc[mi][ni] = fz;

  for (int hb = 0; hb < 16; ++hb) {            // k0 = hb*64
    {
      int row = wv * 8 + subrow;               // A: 32 rows, 1 slot/wave
      gload16(ctxh + ((size_t)hb * MTOT + (m0 + row)) * HDIM + gsw,
              As + (wv * 64 + lane) * 8);
    }
#pragma unroll
    for (int j = 0; j < 4; ++j) {              // B: 128 rows, 4 slots/wave
      int row = (wv * 4 + j) * 8 + subrow;
      gload16(wto + (size_t)(n0 + row) * HID + hb * 64 + gsw,
              Bs + ((wv * 4 + j) * 64 + lane) * 8);
    }
    __syncthreads();
#pragma unroll
    for (int ks = 0; ks < 2; ++ks) {
      const int kc = (((ks * 4 + quad) ^ fsw) * 8);
      bf16x8 af[2], bfr[2];
#pragma unroll
      for (int i = 0; i < 2; ++i) {
        af[i]  = *(const bf16x8*)(&As[(i * 16 + lr) * 64 + kc]);
        bfr[i] = *(const bf16x8*)(&Bs[(wn + i * 16 + lr) * 64 + kc]);
      }
#pragma unroll
      for (int mi = 0; mi < 2; ++mi)
#pragma unroll
        for (int ni = 0; ni < 2; ++ni)
          acc[mi][ni] = __builtin_amdgcn_mfma_f32_16x16x32_bf16(af[mi], bfr[ni], acc[mi][ni], 0, 0, 0);
    }
    __syncthreads();
  }

#pragma unroll
  for (int mi = 0; mi < 2; ++mi) {
    int rowb = m0 + mi * 16 + quad * 4;
#pragma unroll
    for (int r = 0; r < 4; ++r) {
      int row = rowb + r;
      int bb = row / SEQ, ss = row - bb * SEQ;
      const float* res = (ss < LW) ? (word + (size_t)(bb * LW + ss) * HID)
                                   : (ent  + (size_t)(bb * LE + (ss - LW)) * HID);
#pragma unroll
      for (int ni = 0; ni < 2; ++ni) {
        int col = n0 + wn + ni * 16 + lr;
        y[(size_t)row * HID + col] = acc[mi][ni][r] + bo[col] + res[col];
      }
    }
  }
}

// ---------------------------------------------------------------------------
// Kernel 4: LayerNorm per token + scatter into word|entity output split (f32)
// ---------------------------------------------------------------------------
__global__ __launch_bounds__(256) void ln_k(
    const float* __restrict__ y, const float* __restrict__ lnw,
    const float* __restrict__ lnb, float* __restrict__ out)
{
  const int row = blockIdx.x;
  const int tid = threadIdx.x;
  __shared__ float ssum[4], sqq[4];

  const float* yr = y + (size_t)row * HID;
  float4 v = *(const float4*)(yr + tid * 4);
  float s = v.x + v.y + v.z + v.w;
  float q = v.x * v.x + v.y * v.y + v.z * v.z + v.w * v.w;
#pragma unroll
  for (int o = 32; o > 0; o >>= 1) { s += __shfl_xor(s, o); q += __shfl_xor(q, o); }
  if ((tid & 63) == 0) { ssum[tid >> 6] = s; sqq[tid >> 6] = q; }
  __syncthreads();
  s = ssum[0] + ssum[1] + ssum[2] + ssum[3];
  q = sqq[0] + sqq[1] + sqq[2] + sqq[3];
  float mean = s * (1.0f / HID);
  float var  = q * (1.0f / HID) - mean * mean;
  float rstd = rsqrtf(var + 1e-12f);

  int bb = row / SEQ, ss2 = row - bb * SEQ;
  float* dst = (ss2 < LW)
             ? out + (size_t)(bb * LW + ss2) * HID
             : out + (size_t)BATCH * LW * HID + (size_t)(bb * LE + (ss2 - LW)) * HID;

  float4 w4 = *(const float4*)(lnw + tid * 4);
  float4 b4 = *(const float4*)(lnb + tid * 4);
  float4 o4;
  o4.x = w4.x * (v.x - mean) * rstd + b4.x;
  o4.y = w4.y * (v.y - mean) * rstd + b4.y;
  o4.z = w4.z * (v.z - mean) * rstd + b4.z;
  o4.w = w4.w * (v.w - mean) * rstd + b4.w;
  *(float4*)(dst + tid * 4) = o4;
}

// ---------------------------------------------------------------------------
extern "C" void kernel_launch(void* const* d_in, const int* in_sizes, int n_in,
                              void* d_out, int out_size, void* d_ws, size_t ws_size,
                              hipStream_t stream) {
  const float* word = (const float*)d_in[0];
  const float* ent  = (const float*)d_in[1];
  const float* mask = (const float*)d_in[2];
  const float* Wq   = (const float*)d_in[3];
  const float* bq   = (const float*)d_in[4];
  const float* Wk   = (const float*)d_in[5];
  const float* bk   = (const float*)d_in[6];
  const float* Wv   = (const float*)d_in[7];
  const float* bv   = (const float*)d_in[8];
  const float* Wo   = (const float*)d_in[9];
  const float* bo   = (const float*)d_in[10];
  const float* lnw  = (const float*)d_in[11];
  const float* lnb  = (const float*)d_in[12];

  char* base = (char*)d_ws;
  u16*   wt   = (u16*)base;                               // 8 MB
  u16*   q_ws = (u16*)(base + (size_t)8 * 1024 * 1024);   // 9.44 MB each
  u16*   k_ws = q_ws + (size_t)MTOT * HID;
  u16*   v_ws = k_ws + (size_t)MTOT * HID;
  u16*   ctxh = v_ws + (size_t)MTOT * HID;                // [h][M][64]
  char*  xy   = (char*)(ctxh + (size_t)MTOT * HID);
  u16*   xb   = (u16*)xy;                                 // aliases y (disjoint life)
  float* y    = (float*)xy;

  hipLaunchKernelGGL(prep_k, dim3(4096 + MTOT), dim3(256), 0, stream,
                     Wq, Wk, Wv, Wo, wt, word, ent, xb);
  hipLaunchKernelGGL(qkv_gemm_k, dim3(MTOT / 128, HID / 128, 3), dim3(256), 0, stream,
                     xb, wt, bq, bk, bv, q_ws, k_ws, v_ws);
  hipLaunchKernelGGL(attn_k, dim3(BATCH * NHEADS, SEQ / 64), dim3(256), 0, stream,
                     q_ws, k_ws, v_ws, mask, ctxh);
  hipLaunchKernelGGL(out_gemm_k, dim3(MTOT / 32, HID / 128), dim3(256), 0, stream,
                     ctxh, wt + (size_t)3 * HID * HID, bo, word, ent, y);
  hipLaunchKernelGGL(ln_k, dim3(MTOT), dim3(256), 0, stream,
                     y, lnw, lnb, (float*)d_out);
}